// Round 17
// baseline (95.106 us; speedup 1.0000x reference)
//
#include <hip/hip_runtime.h>

#define NBOX   2048
#define HALF   1024
#define MAXDET 100
#define NIMG   8
#define POOL   256
// midpoint(0.3f, nextafterf(0.3f,+inf)) in double:
// RN_f32(inter/denom) > 0.3f  <=>  inter > IOU_MID * denom
// (25-bit mid x 24-bit denom product exact in f64; tie rounds-to-even to 0.3f -> "false" matches)
#define IOU_MID 0x1.333335p-2

typedef unsigned long long u64;

__device__ __forceinline__ u64 shx64(u64 v, int m) {
    int lo = __shfl_xor((int)(unsigned int)v, m, 64);
    int hi = __shfl_xor((int)(unsigned int)(v >> 32), m, 64);
    return ((u64)(unsigned int)hi << 32) | (unsigned int)lo;
}
// bitonic keep rule: take_max ? max(mine, part) : min(mine, part); keys unique
__device__ __forceinline__ u64 cmpsel(u64 mine, u64 part, bool take_max) {
    return ((mine > part) == take_max) ? mine : part;
}
__device__ __forceinline__ u64 readlane64(u64 v, int l) {
    unsigned int lo = (unsigned int)__builtin_amdgcn_readlane((int)(unsigned int)v, l);
    unsigned int hi = (unsigned int)__builtin_amdgcn_readlane((int)(v >> 32), l);
    return ((u64)hi << 32) | lo;
}
__device__ __forceinline__ u64 mkkey(float4 v, float s, int i) {
    bool valid = ((v.z - v.x) >= 25.0f) && ((v.w - v.y) >= 25.0f) && (s >= 0.001f);
    unsigned int sk = valid ? __float_as_uint(s) : 0u;  // scores in [0,1): bits monotone
    return ((u64)sk << 32) | (unsigned int)(~i);
}

// One block per image, 512 threads. No workspace, no cross-block traffic:
// dual interleaved half-sort (LDS) -> top-256 prune-merge -> suppression
// matrix -> wave-0 serial scan -> LDS-resident exact tail -> padding fill.
__global__ __launch_bounds__(512) void k_all(
    const float* __restrict__ boxes, const float* __restrict__ scores,
    float* __restrict__ out)
{
    __shared__ u64    bufA[NBOX];         // 16 KB; ends holding both sorted halves
    __shared__ u64    bufB[NBOX];         // 16 KB; sort double buffer
    __shared__ u64    supRow[POOL * 4];   // 8 KB suppression matrix (bits j>i only)
    __shared__ float4 sbox[POOL];         // 4 KB sorted top-256 boxes
    __shared__ u64    mA[POOL], mB[POOL]; // merge scratch (4 KB)
    __shared__ u64    validW[4];
    __shared__ u64    pminS;
    __shared__ float4 leadersB[MAXDET];
    __shared__ float  leadersA[MAXDET];

    const int g    = threadIdx.x;         // 0..511
    const int lane = g & 63;
    const int wv   = g >> 6;              // 0..7
    const int img  = blockIdx.x;
    const float4* bb4 = (const float4*)boxes + img * NBOX;
    const float*  ss  = scores + img * NBOX;

    // Phase A: 4 keys/thread. k0,k1 = half A elements e0,e0+1 (global idx 0..1023);
    // k2,k3 = half B elements (global idx 1024+e0, 1024+e0+1).
    // key = (score_bits << 32) | ~idx : desc sort == (score desc, idx asc);
    // invalid -> hi = 0 (sorts last, same as -inf).
    const int e0 = 2 * g;
    u64 k0, k1, k2, k3;
    { float4 v = bb4[e0];            k0 = mkkey(v, ss[e0],            e0);            }
    { float4 v = bb4[e0 + 1];        k1 = mkkey(v, ss[e0 + 1],        e0 + 1);        }
    { float4 v = bb4[HALF + e0];     k2 = mkkey(v, ss[HALF + e0],     HALF + e0);     }
    { float4 v = bb4[HALF + e0 + 1]; k3 = mkkey(v, ss[HALF + e0 + 1], HALF + e0 + 1); }

    // Phase B: both halves sorted desc by the SAME network, interleaved
    // (identical direction predicates: they depend only on e within the half).
    // R15-proven stage structure: j=1 reg, j=2..64 shuffle, j>=128 LDS (6 stages).
#define SWAP1(a, b, D) { if ((D) ? ((a) < (b)) : ((a) > (b))) { u64 t_ = (a); (a) = (b); (b) = t_; } }
    { bool D = ((g & 1) == 0); SWAP1(k0, k1, D) SWAP1(k2, k3, D) }   // k=2
    for (int KB = 2; KB <= 64; KB <<= 1) {
        bool D = ((g & KB) == 0);                    // descending-region bit of g
        for (int m = KB >> 1; m >= 1; m >>= 1) {
            bool tm = (D == ((lane & m) == 0));
            k0 = cmpsel(k0, shx64(k0, m), tm);
            k1 = cmpsel(k1, shx64(k1, m), tm);
            k2 = cmpsel(k2, shx64(k2, m), tm);
            k3 = cmpsel(k3, shx64(k3, m), tm);
        }
        SWAP1(k0, k1, D) SWAP1(k2, k3, D)
    }
    int sp = 0;
    for (int K = 256; K <= 1024; K <<= 1) {
        bool D = ((e0 & K) == 0);                    // wave-uniform
        for (int j = K >> 1; j >= 128; j >>= 1) {    // LDS stages (6 total)
            u64* buf = (sp & 1) ? bufB : bufA;
            ++sp;
            buf[e0] = k0;        buf[e0 + 1] = k1;
            buf[HALF + e0] = k2; buf[HALF + e0 + 1] = k3;
            __syncthreads();
            int pe = e0 ^ j;
            u64 p0 = buf[pe], p1 = buf[pe + 1];
            u64 p2 = buf[HALF + pe], p3 = buf[HALF + pe + 1];
            bool tm = (D == ((e0 & j) == 0));        // wave-uniform
            k0 = cmpsel(k0, p0, tm); k1 = cmpsel(k1, p1, tm);
            k2 = cmpsel(k2, p2, tm); k3 = cmpsel(k3, p3, tm);
        }
        for (int m = 32; m >= 1; m >>= 1) {
            bool tm = (D == ((lane & m) == 0));
            k0 = cmpsel(k0, shx64(k0, m), tm);
            k1 = cmpsel(k1, shx64(k1, m), tm);
            k2 = cmpsel(k2, shx64(k2, m), tm);
            k3 = cmpsel(k3, shx64(k3, m), tm);
        }
        SWAP1(k0, k1, D) SWAP1(k2, k3, D)
    }
    // Publish both sorted halves to bufA. Safe: the last LDS stage's barrier
    // (in bufB) separates all earlier bufA reads from these writes.
    bufA[e0] = k0;        bufA[e0 + 1] = k1;
    bufA[HALF + e0] = k2; bufA[HALF + e0 + 1] = k3;
    __syncthreads();

    const u64* hk = bufA;   // sorted halves, LDS-resident

    // Top-256 prune-merge (R15-proven): C[e] = max(A[e], B[255-e]) is the
    // top-256 multiset of the two sorted halves and bitonic; then descending
    // bitonic merge: take_max iff (e & j) == 0; j=128,64 via LDS, rest shuffles.
    u64 c = 0;
    if (g < POOL) {
        u64 a  = hk[g];
        u64 bq = hk[HALF + (POOL - 1 - g)];
        c = (a > bq) ? a : bq;
        mA[g] = c;
    }
    __syncthreads();
    if (g < POOL) { c = cmpsel(c, mA[g ^ 128], (g & 128) == 0); mB[g] = c; }
    __syncthreads();
    if (g < POOL) {                      // waves 0..3 fully active: ballot safe
        c = cmpsel(c, mB[g ^ 64], (g & 64) == 0);
        for (int m = 32; m >= 1; m >>= 1)
            c = cmpsel(c, shx64(c, m), (lane & m) == 0);
        unsigned int idx = ~(unsigned int)c;
        float4 v = bb4[idx];
        sbox[g] = v;
        u64 bal = __ballot(((unsigned int)(c >> 32)) != 0u);
        if (lane == 0) validW[wv] = bal;
        if (g == POOL - 1) pminS = c;
    }
    __syncthreads();

    // Column cache: lane holds boxes at sorted positions 64*w + lane, w = 0..3.
    float4 cb[4];
    float  ca[4];
#pragma unroll
    for (int w = 0; w < 4; ++w) {
        float4 v = sbox[(w << 6) + lane];
        cb[w] = v;
        ca[w] = (v.z - v.x) * (v.w - v.y);
    }

    // Matrix build (R10-proven row math), 8 waves: wave wv owns rows i = 8r + wv.
    // supRow[i][w] bit l = (64w+l > i) && IoU(box_i, box_{64w+l}) > 0.3 (exact).
    // Words w < i>>6 left unwritten; the scan never consumes them.
    for (int r = 0; r < POOL / 8; ++r) {
        int i = (r << 3) + wv;
        float4 Li = sbox[i];              // wave-uniform broadcast read
        float La = (Li.z - Li.x) * (Li.w - Li.y);
        int w0 = i >> 6;                  // wave-uniform
#pragma unroll
        for (int w = 0; w < 4; ++w) {
            if (w >= w0) {                // wave-uniform condition: ballot safe
                int j0 = (w << 6) + lane;
                float iw = fminf(Li.z, cb[w].z) - fmaxf(Li.x, cb[w].x);
                float ih = fminf(Li.w, cb[w].w) - fmaxf(Li.y, cb[w].y);
                iw = fmaxf(iw, 0.0f);
                ih = fmaxf(ih, 0.0f);
                float inter = iw * ih;
                float denom = (La + ca[w]) - inter;   // ref op order: (a_i + a_j) - inter
                bool hit = (j0 > i) && ((double)inter > IOU_MID * (double)denom);
                u64 bits = __ballot(hit);
                if (lane == 0) supRow[(i << 2) + w] = bits;
            }
        }
    }
    __syncthreads();

    if (g >= 64) return;   // wave 0 finishes alone; no barriers below

    float* regions = out;
    float* maskv   = out + (size_t)NIMG * MAXDET * 5;
    int nkept = 0;

    // Serial scan (R13-proven): chain per keeper = ctz -> uniform ds_read of the
    // diagonal word -> andn -> ctz. Full-row fold into pend runs off-chain.
    u64 pend = 0;          // lane accumulates word (lane & 3)
    bool done = false;
    for (int s = 0; s < 4 && !done; ++s) {
        u64 mcur = validW[s] & ~readlane64(pend, s);
        while (mcur) {
            int il = (int)__builtin_ctzll(mcur);
            int i = (s << 6) + il;                     // next keeper in greedy order
            float4 Lb = sbox[i];                       // uniform (off the mask chain)
            if (lane == 0) {
                float* rr = regions + ((size_t)(img * MAXDET + nkept)) * 5;
                rr[0] = (float)img; rr[1] = Lb.x; rr[2] = Lb.y; rr[3] = Lb.z; rr[4] = Lb.w;
                maskv[img * MAXDET + nkept] = 1.0f;
                leadersB[nkept] = Lb;
                leadersA[nkept] = (Lb.z - Lb.x) * (Lb.w - Lb.y);
            }
            nkept++;
            if (nkept >= MAXDET) { done = true; break; }
            u64 rowS = supRow[(i << 2) + s];           // uniform broadcast (chain)
            u64 rowv = supRow[(i << 2) + (lane & 3)];  // off-chain full row
            pend |= rowv;
            mcur = (mcur & (mcur - 1)) & ~rowS;        // bits j<=i of rowS are 0 by build
        }
    }

    // Tail (exact, cold, now LDS-resident): keys below poolMin in desc order
    // via 2-way merge of the sorted halves, tested vs recorded leaders
    // (sufficient state: greedy NMS suppression comes only from kept boxes).
    if (nkept < MAXDET) {
        u64 pmin = pminS;                              // pool = keys >= pmin
        int q0 = 0, q1 = 0;
        while (q0 < HALF && hk[q0] >= pmin) ++q0;
        while (q1 < HALF && hk[HALF + q1] >= pmin) ++q1;
        while (nkept < MAXDET) {
            u64 h0 = (q0 < HALF) ? hk[q0] : 0;
            u64 h1 = (q1 < HALF) ? hk[HALF + q1] : 0;
            u64 hmax = (h0 > h1) ? h0 : h1;
            if ((unsigned int)(hmax >> 32) == 0u) break;   // invalids sort last
            if (hmax == h0) ++q0; else ++q1;
            unsigned int idx = ~(unsigned int)hmax;
            float4 v = bb4[idx];
            float varea = (v.z - v.x) * (v.w - v.y);
            bool sup = false;
            for (int t = lane; t < nkept; t += 64) {
                float4 Lb = leadersB[t];
                float  La = leadersA[t];
                float iw = fminf(Lb.z, v.z) - fmaxf(Lb.x, v.x);
                float ih = fminf(Lb.w, v.w) - fmaxf(Lb.y, v.y);
                iw = fmaxf(iw, 0.0f);
                ih = fmaxf(ih, 0.0f);
                float inter = iw * ih;
                float denom = (La + varea) - inter;
                if ((double)inter > IOU_MID * (double)denom) sup = true;
            }
            if (__ballot(sup) == 0ULL) {
                if (lane == 0) {
                    float* rr = regions + ((size_t)(img * MAXDET + nkept)) * 5;
                    rr[0] = (float)img; rr[1] = v.x; rr[2] = v.y; rr[3] = v.z; rr[4] = v.w;
                    maskv[img * MAXDET + nkept] = 1.0f;
                    leadersB[nkept] = v;
                    leadersA[nkept] = varea;
                }
                nkept++;
            }
        }
    }

    // Padding fill (d_out is poisoned before every launch).
    for (int r = nkept + lane; r < MAXDET; r += 64) {
        float* rr = regions + ((size_t)(img * MAXDET + r)) * 5;
        rr[0] = (float)img; rr[1] = 0.0f; rr[2] = 0.0f; rr[3] = 0.0f; rr[4] = 0.0f;
        maskv[img * MAXDET + r] = 0.0f;
    }
}

extern "C" void kernel_launch(void* const* d_in, const int* in_sizes, int n_in,
                              void* d_out, int out_size, void* d_ws, size_t ws_size,
                              hipStream_t stream) {
    const float* boxes  = (const float*)d_in[0];  // [8,2048,4] f32
    const float* scores = (const float*)d_in[1];  // [8,2048]   f32
    float* out = (float*)d_out;                   // 4800 f32: regions(4000) ++ mask(800)
    k_all<<<NIMG, 512, 0, stream>>>(boxes, scores, out);
}

// Round 18
// 83.248 us; speedup vs baseline: 1.1424x; 1.1424x over previous
//
#include <hip/hip_runtime.h>

#define NBOX   2048
#define HALF   1024
#define MAXDET 100
#define NIMG   8
#define POOL   256
// midpoint(0.3f, nextafterf(0.3f,+inf)) in double:
// RN_f32(inter/denom) > 0.3f  <=>  inter > IOU_MID * denom
// (25-bit mid x 24-bit denom product exact in f64; tie rounds-to-even to 0.3f -> "false" matches)
#define IOU_MID 0x1.333335p-2

typedef unsigned long long u64;

__device__ __forceinline__ u64 shx64(u64 v, int m) {
    int lo = __shfl_xor((int)(unsigned int)v, m, 64);
    int hi = __shfl_xor((int)(unsigned int)(v >> 32), m, 64);
    return ((u64)(unsigned int)hi << 32) | (unsigned int)lo;
}
// bitonic keep rule: take_max ? max(mine, part) : min(mine, part); keys unique
__device__ __forceinline__ u64 cmpsel(u64 mine, u64 part, bool take_max) {
    return ((mine > part) == take_max) ? mine : part;
}
__device__ __forceinline__ u64 readlane64(u64 v, int l) {
    unsigned int lo = (unsigned int)__builtin_amdgcn_readlane((int)(unsigned int)v, l);
    unsigned int hi = (unsigned int)__builtin_amdgcn_readlane((int)(v >> 32), l);
    return ((u64)hi << 32) | lo;
}
__device__ __forceinline__ u64 mkkey(float4 v, float s, int i) {
    bool valid = ((v.z - v.x) >= 25.0f) && ((v.w - v.y) >= 25.0f) && (s >= 0.001f);
    unsigned int sk = valid ? __float_as_uint(s) : 0u;  // scores in [0,1): bits monotone
    return ((u64)sk << 32) | (unsigned int)(~i);
}

// One block per image, 512 threads (R17-proven structure). New in R18: the
// wave-0 scan is a pure SALU/readlane chain (no LDS on the critical path);
// outputs and leader staging run in a parallel post-pass.
__global__ __launch_bounds__(512) void k_all(
    const float* __restrict__ boxes, const float* __restrict__ scores,
    float* __restrict__ out)
{
    __shared__ u64    bufA[NBOX];         // 16 KB; ends holding both sorted halves
    __shared__ u64    bufB[NBOX];         // 16 KB; sort double buffer
    __shared__ u64    supRow[POOL * 4];   // 8 KB suppression matrix (bits j>i only)
    __shared__ float4 sbox[POOL];         // 4 KB sorted top-256 boxes
    __shared__ u64    mA[POOL], mB[POOL]; // merge scratch (4 KB)
    __shared__ u64    validW[4];
    __shared__ u64    pminS;
    __shared__ int    kposL[MAXDET];      // keeper positions (sorted order)
    __shared__ float4 leadersB[MAXDET];
    __shared__ float  leadersA[MAXDET];

    const int g    = threadIdx.x;         // 0..511
    const int lane = g & 63;
    const int wv   = g >> 6;              // 0..7
    const int img  = blockIdx.x;
    const float4* bb4 = (const float4*)boxes + img * NBOX;
    const float*  ss  = scores + img * NBOX;

    // Phase A: 4 keys/thread. k0,k1 = half A elements e0,e0+1; k2,k3 = half B.
    // key = (score_bits << 32) | ~idx : desc sort == (score desc, idx asc);
    // invalid -> hi = 0 (sorts last, same as -inf).
    const int e0 = 2 * g;
    u64 k0, k1, k2, k3;
    { float4 v = bb4[e0];            k0 = mkkey(v, ss[e0],            e0);            }
    { float4 v = bb4[e0 + 1];        k1 = mkkey(v, ss[e0 + 1],        e0 + 1);        }
    { float4 v = bb4[HALF + e0];     k2 = mkkey(v, ss[HALF + e0],     HALF + e0);     }
    { float4 v = bb4[HALF + e0 + 1]; k3 = mkkey(v, ss[HALF + e0 + 1], HALF + e0 + 1); }

    // Phase B (R17-proven): both halves sorted desc by the SAME network,
    // interleaved. j=1 reg, j=2..64 shuffle, j>=128 LDS (6 stages).
#define SWAP1(a, b, D) { if ((D) ? ((a) < (b)) : ((a) > (b))) { u64 t_ = (a); (a) = (b); (b) = t_; } }
    { bool D = ((g & 1) == 0); SWAP1(k0, k1, D) SWAP1(k2, k3, D) }   // k=2
    for (int KB = 2; KB <= 64; KB <<= 1) {
        bool D = ((g & KB) == 0);                    // descending-region bit of g
        for (int m = KB >> 1; m >= 1; m >>= 1) {
            bool tm = (D == ((lane & m) == 0));
            k0 = cmpsel(k0, shx64(k0, m), tm);
            k1 = cmpsel(k1, shx64(k1, m), tm);
            k2 = cmpsel(k2, shx64(k2, m), tm);
            k3 = cmpsel(k3, shx64(k3, m), tm);
        }
        SWAP1(k0, k1, D) SWAP1(k2, k3, D)
    }
    int sp = 0;
    for (int K = 256; K <= 1024; K <<= 1) {
        bool D = ((e0 & K) == 0);                    // wave-uniform
        for (int j = K >> 1; j >= 128; j >>= 1) {    // LDS stages (6 total)
            u64* buf = (sp & 1) ? bufB : bufA;
            ++sp;
            buf[e0] = k0;        buf[e0 + 1] = k1;
            buf[HALF + e0] = k2; buf[HALF + e0 + 1] = k3;
            __syncthreads();
            int pe = e0 ^ j;
            u64 p0 = buf[pe], p1 = buf[pe + 1];
            u64 p2 = buf[HALF + pe], p3 = buf[HALF + pe + 1];
            bool tm = (D == ((e0 & j) == 0));        // wave-uniform
            k0 = cmpsel(k0, p0, tm); k1 = cmpsel(k1, p1, tm);
            k2 = cmpsel(k2, p2, tm); k3 = cmpsel(k3, p3, tm);
        }
        for (int m = 32; m >= 1; m >>= 1) {
            bool tm = (D == ((lane & m) == 0));
            k0 = cmpsel(k0, shx64(k0, m), tm);
            k1 = cmpsel(k1, shx64(k1, m), tm);
            k2 = cmpsel(k2, shx64(k2, m), tm);
            k3 = cmpsel(k3, shx64(k3, m), tm);
        }
        SWAP1(k0, k1, D) SWAP1(k2, k3, D)
    }
    // Publish both sorted halves to bufA (fenced by the last LDS stage barrier).
    bufA[e0] = k0;        bufA[e0 + 1] = k1;
    bufA[HALF + e0] = k2; bufA[HALF + e0 + 1] = k3;
    __syncthreads();

    const u64* hk = bufA;   // sorted halves, LDS-resident

    // Top-256 prune-merge (R15-proven): C[e] = max(A[e], B[255-e]) is the
    // top-256 multiset and bitonic; descending merge: take_max iff (e&j)==0.
    u64 c = 0;
    if (g < POOL) {
        u64 a  = hk[g];
        u64 bq = hk[HALF + (POOL - 1 - g)];
        c = (a > bq) ? a : bq;
        mA[g] = c;
    }
    __syncthreads();
    if (g < POOL) { c = cmpsel(c, mA[g ^ 128], (g & 128) == 0); mB[g] = c; }
    __syncthreads();
    if (g < POOL) {                      // waves 0..3 fully active: ballot safe
        c = cmpsel(c, mB[g ^ 64], (g & 64) == 0);
        for (int m = 32; m >= 1; m >>= 1)
            c = cmpsel(c, shx64(c, m), (lane & m) == 0);
        unsigned int idx = ~(unsigned int)c;
        float4 v = bb4[idx];
        sbox[g] = v;
        u64 bal = __ballot(((unsigned int)(c >> 32)) != 0u);
        if (lane == 0) validW[wv] = bal;
        if (g == POOL - 1) pminS = c;
    }
    __syncthreads();

    // Column cache: lane holds boxes at sorted positions 64*w + lane, w = 0..3.
    float4 cb[4];
    float  ca[4];
#pragma unroll
    for (int w = 0; w < 4; ++w) {
        float4 v = sbox[(w << 6) + lane];
        cb[w] = v;
        ca[w] = (v.z - v.x) * (v.w - v.y);
    }

    // Matrix build (R10-proven row math), 8 waves: wave wv owns rows i = 8r + wv.
    // supRow[i][w] bit l = (64w+l > i) && IoU(box_i, box_{64w+l}) > 0.3 (exact).
    // Words w < i>>6 left unwritten; never consumed.
    for (int r = 0; r < POOL / 8; ++r) {
        int i = (r << 3) + wv;
        float4 Li = sbox[i];              // wave-uniform broadcast read
        float La = (Li.z - Li.x) * (Li.w - Li.y);
        int w0 = i >> 6;                  // wave-uniform
#pragma unroll
        for (int w = 0; w < 4; ++w) {
            if (w >= w0) {                // wave-uniform condition: ballot safe
                int j0 = (w << 6) + lane;
                float iw = fminf(Li.z, cb[w].z) - fmaxf(Li.x, cb[w].x);
                float ih = fminf(Li.w, cb[w].w) - fmaxf(Li.y, cb[w].y);
                iw = fmaxf(iw, 0.0f);
                ih = fmaxf(ih, 0.0f);
                float inter = iw * ih;
                float denom = (La + ca[w]) - inter;   // ref op order: (a_i + a_j) - inter
                bool hit = (j0 > i) && ((double)inter > IOU_MID * (double)denom);
                u64 bits = __ballot(hit);
                if (lane == 0) supRow[(i << 2) + w] = bits;
            }
        }
    }
    __syncthreads();

    if (g >= 64) return;   // wave 0 finishes alone; no barriers below

    float* regions = out;
    float* maskv   = out + (size_t)NIMG * MAXDET * 5;

    // ---- Scan (NEW): pure SALU/readlane chain. Lane l preloads the diagonal
    // word of row (s<<6)+l for each segment; the keeper chain is
    // ctz -> v_readlane -> andn (no LDS). kposL records keepers (off-chain
    // ds_write); pend (word lane&3) is folded ONLY at segment boundaries from
    // the new keepers' rows, 64 lanes in parallel + shuffle-OR butterfly.
    // Semantics identical to R17's scan.
    u64 rd0 = supRow[(((0 << 6) + lane) << 2) + 0];
    u64 rd1 = supRow[(((1 << 6) + lane) << 2) + 1];
    u64 rd2 = supRow[(((2 << 6) + lane) << 2) + 2];
    u64 rd3 = supRow[(((3 << 6) + lane) << 2) + 3];

    int nkept = 0;
    u64 pend = 0;          // lane accumulates word (lane & 3)
#pragma unroll
    for (int s = 0; s < 4; ++s) {
        u64 rds = (s == 0) ? rd0 : (s == 1) ? rd1 : (s == 2) ? rd2 : rd3;
        u64 mcur = validW[s] & ~readlane64(pend, s);
        int n0 = nkept;
        while (mcur != 0ULL) {
            int il = (int)__builtin_ctzll(mcur);       // uniform (SALU)
            if (lane == 0) kposL[nkept] = (s << 6) + il;
            nkept++;
            if (nkept >= MAXDET) break;
            u64 rowS = readlane64(rds, il);            // register broadcast
            mcur = (mcur & (mcur - 1)) & ~rowS;        // bits j<=i of rowS are 0
        }
        if (nkept >= MAXDET) break;
        if (s < 3) {
            // fold new keepers' rows: lane group 4q..4q+3 covers keeper q's words
            for (int t = n0 + (lane >> 2); t < nkept; t += 16)
                pend |= supRow[(kposL[t] << 2) + (lane & 3)];
            pend |= shx64(pend, 4);
            pend |= shx64(pend, 8);
            pend |= shx64(pend, 16);
            pend |= shx64(pend, 32);   // now uniform within each mod-4 lane group
        }
    }

    // ---- Output pass (NEW): parallel across lanes; also stages tail leaders.
    for (int t = lane; t < nkept; t += 64) {
        int ip = kposL[t];
        float4 v = sbox[ip];
        float* rr = regions + ((size_t)(img * MAXDET + t)) * 5;
        rr[0] = (float)img; rr[1] = v.x; rr[2] = v.y; rr[3] = v.z; rr[4] = v.w;
        maskv[img * MAXDET + t] = 1.0f;
        leadersB[t] = v;
        leadersA[t] = (v.z - v.x) * (v.w - v.y);
    }

    // Tail (exact, cold, LDS-resident; R17-proven): keys below poolMin in desc
    // order via 2-way merge of the sorted halves, tested vs recorded leaders.
    if (nkept < MAXDET) {
        u64 pmin = pminS;                              // pool = keys >= pmin
        int q0 = 0, q1 = 0;
        while (q0 < HALF && hk[q0] >= pmin) ++q0;
        while (q1 < HALF && hk[HALF + q1] >= pmin) ++q1;
        while (nkept < MAXDET) {
            u64 h0 = (q0 < HALF) ? hk[q0] : 0;
            u64 h1 = (q1 < HALF) ? hk[HALF + q1] : 0;
            u64 hmax = (h0 > h1) ? h0 : h1;
            if ((unsigned int)(hmax >> 32) == 0u) break;   // invalids sort last
            if (hmax == h0) ++q0; else ++q1;
            unsigned int idx = ~(unsigned int)hmax;
            float4 v = bb4[idx];
            float varea = (v.z - v.x) * (v.w - v.y);
            bool sup = false;
            for (int t = lane; t < nkept; t += 64) {
                float4 Lb = leadersB[t];
                float  La = leadersA[t];
                float iw = fminf(Lb.z, v.z) - fmaxf(Lb.x, v.x);
                float ih = fminf(Lb.w, v.w) - fmaxf(Lb.y, v.y);
                iw = fmaxf(iw, 0.0f);
                ih = fmaxf(ih, 0.0f);
                float inter = iw * ih;
                float denom = (La + varea) - inter;
                if ((double)inter > IOU_MID * (double)denom) sup = true;
            }
            if (__ballot(sup) == 0ULL) {
                if (lane == 0) {
                    float* rr = regions + ((size_t)(img * MAXDET + nkept)) * 5;
                    rr[0] = (float)img; rr[1] = v.x; rr[2] = v.y; rr[3] = v.z; rr[4] = v.w;
                    maskv[img * MAXDET + nkept] = 1.0f;
                    leadersB[nkept] = v;
                    leadersA[nkept] = varea;
                }
                nkept++;
            }
        }
    }

    // Padding fill (d_out is poisoned before every launch).
    for (int r = nkept + lane; r < MAXDET; r += 64) {
        float* rr = regions + ((size_t)(img * MAXDET + r)) * 5;
        rr[0] = (float)img; rr[1] = 0.0f; rr[2] = 0.0f; rr[3] = 0.0f; rr[4] = 0.0f;
        maskv[img * MAXDET + r] = 0.0f;
    }
}

extern "C" void kernel_launch(void* const* d_in, const int* in_sizes, int n_in,
                              void* d_out, int out_size, void* d_ws, size_t ws_size,
                              hipStream_t stream) {
    const float* boxes  = (const float*)d_in[0];  // [8,2048,4] f32
    const float* scores = (const float*)d_in[1];  // [8,2048]   f32
    float* out = (float*)d_out;                   // 4800 f32: regions(4000) ++ mask(800)
    k_all<<<NIMG, 512, 0, stream>>>(boxes, scores, out);
}